// Round 7
// baseline (2437.988 us; speedup 1.0000x reference)
//
#include <hip/hip_runtime.h>

#define B_ 4
#define S_ 2048
#define T_ (B_*S_)      // 8192 tokens
#define D_ 1024
#define E_ 8
#define F_ 4096
#define K_ 2
#define TK_ (T_*K_)     // 16384 slots

typedef __attribute__((ext_vector_type(8))) short short8;
typedef __attribute__((ext_vector_type(4))) float f32x4;

__device__ __forceinline__ unsigned short bf16rn(float f) {
    unsigned int u = __builtin_bit_cast(unsigned int, f);
    u = u + 0x7FFFu + ((u >> 16) & 1u);
    return (unsigned short)(u >> 16);
}
__device__ __forceinline__ float bf16tof(unsigned short h) {
    unsigned int u = ((unsigned int)h) << 16;
    return __builtin_bit_cast(float, u);
}

#define GLOAD16(gp, lp) __builtin_amdgcn_global_load_lds( \
    (const __attribute__((address_space(1))) unsigned int*)(gp), \
    (__attribute__((address_space(3))) unsigned int*)(lp), 16, 0, 0)

// ---------------- gating: logits -> softmax -> top2 -> renorm ----------------
__global__ void gate_kernel(const float* __restrict__ x, const float* __restrict__ gw,
                            const float* __restrict__ gb, int* __restrict__ topi,
                            float* __restrict__ topw, int* __restrict__ counts)
{
    const int gid  = blockIdx.x * blockDim.x + threadIdx.x;
    const int t    = gid >> 6;            // one wave per token
    const int lane = threadIdx.x & 63;
    if (t >= T_) return;
    const float* xr = x + (size_t)t * D_;
    float p[E_];
#pragma unroll
    for (int e = 0; e < E_; ++e) p[e] = 0.f;
    for (int j = 0; j < D_ / 64; ++j) {
        const int d = j * 64 + lane;
        const float xv = xr[d];
        const float* g = gw + (size_t)d * E_;
#pragma unroll
        for (int e = 0; e < E_; ++e) p[e] += xv * g[e];
    }
#pragma unroll
    for (int off = 32; off > 0; off >>= 1) {
#pragma unroll
        for (int e = 0; e < E_; ++e) p[e] += __shfl_xor(p[e], off);
    }
    if (lane == 0) {
#pragma unroll
        for (int e = 0; e < E_; ++e) p[e] += gb[e];
        float m = p[0];
#pragma unroll
        for (int e = 1; e < E_; ++e) m = fmaxf(m, p[e]);
        float ex[E_];
#pragma unroll
        for (int e = 0; e < E_; ++e) ex[e] = expf(p[e] - m);
        int i0 = 0; float v0 = ex[0];
#pragma unroll
        for (int e = 1; e < E_; ++e) if (ex[e] > v0) { v0 = ex[e]; i0 = e; }
        int i1 = -1; float v1 = -1.f;
#pragma unroll
        for (int e = 0; e < E_; ++e) if (e != i0 && ex[e] > v1) { v1 = ex[e]; i1 = e; }
        const float inv = 1.f / (v0 + v1);
        topi[t*2]   = i0; topi[t*2+1] = i1;
        topw[t*2]   = v0 * inv; topw[t*2+1] = v1 * inv;
        atomicAdd(&counts[i0], 1);
        atomicAdd(&counts[i1], 1);
    }
}

__global__ void offsets_kernel(const int* __restrict__ counts, int* __restrict__ offsets,
                               int* __restrict__ cursor)
{
    if (threadIdx.x == 0 && blockIdx.x == 0) {
        int acc = 0;
        for (int e = 0; e < E_; ++e) { offsets[e] = acc; cursor[e] = acc; acc += counts[e]; }
    }
}

__global__ void scatter_kernel(const int* __restrict__ topi, const float* __restrict__ topw,
                               int* __restrict__ cursor, int* __restrict__ list_token,
                               float* __restrict__ list_w, int* __restrict__ slot_of)
{
    const int t = blockIdx.x * blockDim.x + threadIdx.x;
    if (t >= T_) return;
#pragma unroll
    for (int k = 0; k < K_; ++k) {
        const int e = topi[t*2 + k];
        const int s = atomicAdd(&cursor[e], 1);
        list_token[s] = t;
        list_w[s]     = topw[t*2 + k];
        slot_of[t*2 + k] = s;
    }
}

// ---------------- converts: fp32 -> split bf16 hi/lo ----------------
__global__ void convert_x_kernel(const float* __restrict__ x,
                                 unsigned short* __restrict__ xh,
                                 unsigned short* __restrict__ xl)
{
    const size_t i = (size_t)blockIdx.x * blockDim.x + threadIdx.x;  // one float4 each
    const float4 v = ((const float4*)x)[i];
    ushort4 h, l;
    h.x = bf16rn(v.x); l.x = bf16rn(v.x - bf16tof(h.x));
    h.y = bf16rn(v.y); l.y = bf16rn(v.y - bf16tof(h.y));
    h.z = bf16rn(v.z); l.z = bf16rn(v.z - bf16tof(h.z));
    h.w = bf16rn(v.w); l.w = bf16rn(v.w - bf16tof(h.w));
    ((ushort4*)xh)[i] = h;
    ((ushort4*)xl)[i] = l;
}

// in [e][R][C] fp32 -> oh/ol [e][C][R] bf16 (transpose+split).
// 64x64 tile per block, 256 threads, each owns a 4x4 micro-tile in registers:
// reads 4x float4 coalesced along C, writes 4x ushort4 along R (32B segments,
// full-line coverage per wave). No LDS, no syncthreads.
__global__ __launch_bounds__(256) void tconv_kernel(const float* __restrict__ in,
                                                    unsigned short* __restrict__ oh,
                                                    unsigned short* __restrict__ ol,
                                                    int R, int C)
{
    const int e = blockIdx.z;
    const size_t eb = (size_t)e * R * C;
    const int r4 = blockIdx.y * 64 + ((threadIdx.x >> 4) << 2);
    const int c4 = blockIdx.x * 64 + ((threadIdx.x & 15) << 2);
    float4 v[4];
#pragma unroll
    for (int i = 0; i < 4; ++i)
        v[i] = *(const float4*)&in[eb + (size_t)(r4 + i) * C + c4];
    const float* vf = (const float*)v;   // vf[i*4+j]
#pragma unroll
    for (int j = 0; j < 4; ++j) {
        ushort4 h, l;
        float f;
        f = vf[0*4+j]; h.x = bf16rn(f); l.x = bf16rn(f - bf16tof(h.x));
        f = vf[1*4+j]; h.y = bf16rn(f); l.y = bf16rn(f - bf16tof(h.y));
        f = vf[2*4+j]; h.z = bf16rn(f); l.z = bf16rn(f - bf16tof(h.z));
        f = vf[3*4+j]; h.w = bf16rn(f); l.w = bf16rn(f - bf16tof(h.w));
        const size_t o = eb + (size_t)(c4 + j) * R + r4;
        *(ushort4*)&oh[o] = h;
        *(ushort4*)&ol[o] = l;
    }
}

// ---------------- MFMA GEMM1: mid = relu(x_gathered @ w1t^T + b1), split-3 ----------------
// 128x128x32 tiles, 4 waves, double-buffered LDS (2 x 4 planes x [128][32] bf16),
// 2-phase schedule: prefetch next K-tile's global_load_lds before ds_read+MFMA.
#define PLANE4 (4*4096)
__global__ __launch_bounds__(256, 2) void gemm1_mfma(
    const unsigned short* __restrict__ xh, const unsigned short* __restrict__ xl,
    const unsigned short* __restrict__ w1h, const unsigned short* __restrict__ w1l,
    const float* __restrict__ b1,
    const int* __restrict__ list_token, const int* __restrict__ offsets,
    const int* __restrict__ counts,
    unsigned short* __restrict__ midh, unsigned short* __restrict__ midl,
    int f0, int Fc)
{
    const int e   = blockIdx.z;
    const int cnt = counts[e];
    const int r0  = blockIdx.x * 128;
    if (r0 >= cnt) return;
    const int base = offsets[e];
    const int fcol = f0 + blockIdx.y * 128;

    __shared__ unsigned short lds[2 * PLANE4];   // 64 KiB

    const int tid = threadIdx.x;
    const int w = tid >> 6, l = tid & 63;

    // --- staging setup: wave w owns plane w (0:Ah 1:Al 2:Bh 3:Bl) ---
    const unsigned short* gsrc[8];
    {
        const unsigned short* Abase = (w == 0) ? xh : xl;
        const unsigned short* Bbase = (w == 2) ? w1h : w1l;
        const int jr = l >> 2, pos = l & 3;
#pragma unroll
        for (int j = 0; j < 8; ++j) {
            const int r  = j * 16 + jr;
            const int kg = pos ^ ((r >> 1) & 3);      // source pre-swizzle (involution)
            if (w < 2) {
                int idx = base + r0 + r; if (idx > TK_ - 1) idx = TK_ - 1;
                const int tok = list_token[idx];
                gsrc[j] = Abase + (size_t)tok * D_ + kg * 8;
            } else {
                gsrc[j] = Bbase + ((size_t)e * F_ + fcol + r) * D_ + kg * 8;
            }
        }
    }

    // --- fragment LDS indices (swizzled read, invariant over k0) ---
    const int wr = w >> 1, wc = w & 1;
    int idxA[4], idxB[4];
#pragma unroll
    for (int m = 0; m < 4; ++m) {
        const int row = wr * 64 + m * 16 + (l & 15);
        const int kgr = (l >> 4) ^ ((row >> 1) & 3);
        idxA[m] = row * 32 + kgr * 8;
    }
#pragma unroll
    for (int n = 0; n < 4; ++n) {
        const int row = wc * 64 + n * 16 + (l & 15);
        const int kgr = (l >> 4) ^ ((row >> 1) & 3);
        idxB[n] = row * 32 + kgr * 8;
    }

    f32x4 acc[4][4];
#pragma unroll
    for (int m = 0; m < 4; ++m)
#pragma unroll
        for (int n = 0; n < 4; ++n) { f32x4 z = {0.f,0.f,0.f,0.f}; acc[m][n] = z; }

    const int NK = D_ / 32;
    // prologue: stage tile 0 into buffer 0
    {
        unsigned short* dst = &lds[w * 4096];
#pragma unroll
        for (int j = 0; j < 8; ++j) GLOAD16(gsrc[j], dst + j * 512);
    }
    for (int kt = 0; kt < NK; ++kt) {
        __syncthreads();                       // drains prev stage; lds[kt&1] ready
        if (kt + 1 < NK) {                     // prefetch next tile into other buffer
            unsigned short* dst = &lds[((kt + 1) & 1) * PLANE4 + w * 4096];
            const int koff = (kt + 1) * 32;
#pragma unroll
            for (int j = 0; j < 8; ++j) GLOAD16(gsrc[j] + koff, dst + j * 512);
        }
        const unsigned short* cur = &lds[(kt & 1) * PLANE4];
        short8 ah[4], al[4], bh[4], bl[4];
#pragma unroll
        for (int m = 0; m < 4; ++m) {
            ah[m] = *(const short8*)&cur[0 * 4096 + idxA[m]];
            al[m] = *(const short8*)&cur[1 * 4096 + idxA[m]];
        }
#pragma unroll
        for (int n = 0; n < 4; ++n) {
            bh[n] = *(const short8*)&cur[2 * 4096 + idxB[n]];
            bl[n] = *(const short8*)&cur[3 * 4096 + idxB[n]];
        }
#pragma unroll
        for (int m = 0; m < 4; ++m)
#pragma unroll
            for (int n = 0; n < 4; ++n) {
                acc[m][n] = __builtin_amdgcn_mfma_f32_16x16x32_bf16(ah[m], bh[n], acc[m][n], 0, 0, 0);
                acc[m][n] = __builtin_amdgcn_mfma_f32_16x16x32_bf16(ah[m], bl[n], acc[m][n], 0, 0, 0);
                acc[m][n] = __builtin_amdgcn_mfma_f32_16x16x32_bf16(al[m], bh[n], acc[m][n], 0, 0, 0);
            }
    }

    // --- epilogue: +bias, relu, split to bf16 hi/lo, store mid ---
    const float* b1e = b1 + (size_t)e * F_;
#pragma unroll
    for (int n = 0; n < 4; ++n) {
        const int fg = fcol + wc * 64 + n * 16 + (l & 15);
        const float bias = b1e[fg];
        const int fl = fg - f0;
#pragma unroll
        for (int m = 0; m < 4; ++m)
#pragma unroll
            for (int q = 0; q < 4; ++q) {
                const int rr = r0 + wr * 64 + m * 16 + (l >> 4) * 4 + q;
                if (rr < cnt) {
                    float v = acc[m][n][q] + bias;
                    v = fmaxf(v, 0.f);
                    const unsigned short h = bf16rn(v);
                    const unsigned short lo = bf16rn(v - bf16tof(h));
                    const size_t o = (size_t)(base + rr) * Fc + fl;
                    midh[o] = h; midl[o] = lo;
                }
            }
    }
}

// ---------------- MFMA GEMM2: part[slot] (+)= lw*(mid @ w2t^T + b2), split-3 ----------------
__global__ __launch_bounds__(256, 2) void gemm2_mfma(
    const unsigned short* __restrict__ midh, const unsigned short* __restrict__ midl,
    const unsigned short* __restrict__ w2h, const unsigned short* __restrict__ w2l,
    const float* __restrict__ b2, const float* __restrict__ list_w,
    const int* __restrict__ offsets, const int* __restrict__ counts,
    float* __restrict__ part, int f0, int Fc, int first)
{
    const int e   = blockIdx.z;
    const int cnt = counts[e];
    const int r0  = blockIdx.x * 128;
    if (r0 >= cnt) return;
    const int base = offsets[e];
    const int dcol = blockIdx.y * 128;

    __shared__ unsigned short lds[2 * PLANE4];

    const int tid = threadIdx.x;
    const int w = tid >> 6, l = tid & 63;

    const unsigned short* gsrc[8];
    {
        const unsigned short* Abase = (w == 0) ? midh : midl;
        const unsigned short* Bbase = (w == 2) ? w2h : w2l;
        const int jr = l >> 2, pos = l & 3;
#pragma unroll
        for (int j = 0; j < 8; ++j) {
            const int r  = j * 16 + jr;
            const int kg = pos ^ ((r >> 1) & 3);
            if (w < 2) {
                int slot = base + r0 + r; if (slot > TK_ - 1) slot = TK_ - 1;
                gsrc[j] = Abase + (size_t)slot * Fc + kg * 8;
            } else {
                gsrc[j] = Bbase + ((size_t)e * D_ + dcol + r) * F_ + f0 + kg * 8;
            }
        }
    }

    const int wr = w >> 1, wc = w & 1;
    int idxA[4], idxB[4];
#pragma unroll
    for (int m = 0; m < 4; ++m) {
        const int row = wr * 64 + m * 16 + (l & 15);
        const int kgr = (l >> 4) ^ ((row >> 1) & 3);
        idxA[m] = row * 32 + kgr * 8;
    }
#pragma unroll
    for (int n = 0; n < 4; ++n) {
        const int row = wc * 64 + n * 16 + (l & 15);
        const int kgr = (l >> 4) ^ ((row >> 1) & 3);
        idxB[n] = row * 32 + kgr * 8;
    }

    f32x4 acc[4][4];
#pragma unroll
    for (int m = 0; m < 4; ++m)
#pragma unroll
        for (int n = 0; n < 4; ++n) { f32x4 z = {0.f,0.f,0.f,0.f}; acc[m][n] = z; }

    const int NK = Fc / 32;
    {
        unsigned short* dst = &lds[w * 4096];
#pragma unroll
        for (int j = 0; j < 8; ++j) GLOAD16(gsrc[j], dst + j * 512);
    }
    for (int kt = 0; kt < NK; ++kt) {
        __syncthreads();
        if (kt + 1 < NK) {
            unsigned short* dst = &lds[((kt + 1) & 1) * PLANE4 + w * 4096];
            const int koff = (kt + 1) * 32;
#pragma unroll
            for (int j = 0; j < 8; ++j) GLOAD16(gsrc[j] + koff, dst + j * 512);
        }
        const unsigned short* cur = &lds[(kt & 1) * PLANE4];
        short8 ah[4], al[4], bh[4], bl[4];
#pragma unroll
        for (int m = 0; m < 4; ++m) {
            ah[m] = *(const short8*)&cur[0 * 4096 + idxA[m]];
            al[m] = *(const short8*)&cur[1 * 4096 + idxA[m]];
        }
#pragma unroll
        for (int n = 0; n < 4; ++n) {
            bh[n] = *(const short8*)&cur[2 * 4096 + idxB[n]];
            bl[n] = *(const short8*)&cur[3 * 4096 + idxB[n]];
        }
#pragma unroll
        for (int m = 0; m < 4; ++m)
#pragma unroll
            for (int n = 0; n < 4; ++n) {
                acc[m][n] = __builtin_amdgcn_mfma_f32_16x16x32_bf16(ah[m], bh[n], acc[m][n], 0, 0, 0);
                acc[m][n] = __builtin_amdgcn_mfma_f32_16x16x32_bf16(ah[m], bl[n], acc[m][n], 0, 0, 0);
                acc[m][n] = __builtin_amdgcn_mfma_f32_16x16x32_bf16(al[m], bh[n], acc[m][n], 0, 0, 0);
            }
    }

    float bias[4]; int dg[4];
#pragma unroll
    for (int n = 0; n < 4; ++n) {
        dg[n] = dcol + wc * 64 + n * 16 + (l & 15);
        bias[n] = b2[(size_t)e * D_ + dg[n]];
    }
#pragma unroll
    for (int m = 0; m < 4; ++m)
#pragma unroll
        for (int q = 0; q < 4; ++q) {
            const int rr = r0 + wr * 64 + m * 16 + (l >> 4) * 4 + q;
            if (rr < cnt) {
                const size_t s = (size_t)(base + rr);
                const float lw = list_w[s];
#pragma unroll
                for (int n = 0; n < 4; ++n) {
                    float v = acc[m][n][q] * lw;
                    if (first) v += lw * bias[n];
                    const size_t o = s * D_ + dg[n];
                    part[o] = first ? v : (part[o] + v);
                }
            }
        }
}

// ---------------- combine ----------------
__global__ void combine_kernel(const float* __restrict__ part, const int* __restrict__ slot_of,
                               float* __restrict__ out)
{
    const int idx = blockIdx.x * blockDim.x + threadIdx.x;
    const int t  = idx >> 8;            // D/4 = 256 float4 per token
    const int dq = idx & 255;
    const float4* p4 = (const float4*)part;
    const float4 a = p4[(size_t)slot_of[t*2]   * 256 + dq];
    const float4 b = p4[(size_t)slot_of[t*2+1] * 256 + dq];
    float4 r; r.x = a.x + b.x; r.y = a.y + b.y; r.z = a.z + b.z; r.w = a.w + b.w;
    ((float4*)out)[(size_t)t * 256 + dq] = r;
}

// ---------------- fallback fp32 GEMMs (used only if ws too small) ----------------
#define TILE 128
#define KSTEP 8
__global__ __launch_bounds__(256) void gemm1_f32(
    const float* __restrict__ x, const float* __restrict__ w1, const float* __restrict__ b1,
    const int* __restrict__ list_token, const int* __restrict__ offsets,
    const int* __restrict__ counts, float* __restrict__ mid, int f0, int Fc)
{
    const int e   = blockIdx.z;
    const int cnt = counts[e];
    const int r0  = blockIdx.x * TILE;
    if (r0 >= cnt) return;
    const int base = offsets[e];
    const int fcol = f0 + blockIdx.y * TILE;
    const int tid  = threadIdx.x;
    __shared__ float As[KSTEP][TILE + 4];
    __shared__ float Bs[KSTEP][TILE + 4];
    const int arow = tid >> 1;
    const int akq  = (tid & 1) * 4;
    const float* aptr = nullptr;
    if (r0 + arow < cnt) aptr = x + (size_t)list_token[base + r0 + arow] * D_;
    const int brow = tid >> 5;
    const int bcol = (tid & 31) * 4;
    const float* bptr = w1 + ((size_t)e * D_ + brow) * F_ + fcol + bcol;
    const int mb = (tid >> 4) * 8, nb = (tid & 15) * 8;
    float acc[8][8];
#pragma unroll
    for (int i = 0; i < 8; ++i)
#pragma unroll
        for (int j = 0; j < 8; ++j) acc[i][j] = 0.f;
    for (int k0 = 0; k0 < D_; k0 += KSTEP) {
        const float4 av = aptr ? *(const float4*)(aptr + k0 + akq) : make_float4(0.f,0.f,0.f,0.f);
        const float4 bv = *(const float4*)(bptr + (size_t)k0 * F_);
        __syncthreads();
        As[akq+0][arow] = av.x; As[akq+1][arow] = av.y;
        As[akq+2][arow] = av.z; As[akq+3][arow] = av.w;
        *(float4*)&Bs[brow][bcol] = bv;
        __syncthreads();
#pragma unroll
        for (int kk = 0; kk < KSTEP; ++kk) {
            const float4 a0 = *(const float4*)&As[kk][mb];
            const float4 a1 = *(const float4*)&As[kk][mb+4];
            const float4 b0 = *(const float4*)&Bs[kk][nb];
            const float4 b1v = *(const float4*)&Bs[kk][nb+4];
            const float af[8] = {a0.x,a0.y,a0.z,a0.w,a1.x,a1.y,a1.z,a1.w};
            const float bf[8] = {b0.x,b0.y,b0.z,b0.w,b1v.x,b1v.y,b1v.z,b1v.w};
#pragma unroll
            for (int i = 0; i < 8; ++i)
#pragma unroll
                for (int j = 0; j < 8; ++j) acc[i][j] = fmaf(af[i], bf[j], acc[i][j]);
        }
    }
    const int fc_local = fcol - f0;
#pragma unroll
    for (int i = 0; i < 8; ++i) {
        const int r = r0 + mb + i;
        if (r < cnt) {
            const size_t s = (size_t)(base + r);
            const size_t off = s * (size_t)Fc + fc_local + nb;
#pragma unroll
            for (int j = 0; j < 8; ++j) {
                const float v = acc[i][j] + b1[(size_t)e * F_ + fcol + nb + j];
                mid[off + j] = fmaxf(v, 0.f);
            }
        }
    }
}

__global__ __launch_bounds__(256) void gemm2_f32(
    const float* __restrict__ mid, const float* __restrict__ w2, const float* __restrict__ b2,
    const float* __restrict__ list_w, const int* __restrict__ offsets,
    const int* __restrict__ counts, float* __restrict__ part, int f0, int Fc, int first)
{
    const int e   = blockIdx.z;
    const int cnt = counts[e];
    const int r0  = blockIdx.x * TILE;
    if (r0 >= cnt) return;
    const int base = offsets[e];
    const int dcol = blockIdx.y * TILE;
    const int tid  = threadIdx.x;
    __shared__ float As[KSTEP][TILE + 4];
    __shared__ float Bs[KSTEP][TILE + 4];
    const int arow = tid >> 1;
    const int akq  = (tid & 1) * 4;
    const float* aptr = nullptr;
    if (r0 + arow < cnt) aptr = mid + (size_t)(base + r0 + arow) * Fc;
    const int brow = tid >> 5;
    const int bcol = (tid & 31) * 4;
    const float* bptr = w2 + ((size_t)e * F_ + f0 + brow) * D_ + dcol + bcol;
    const int mb = (tid >> 4) * 8, nb = (tid & 15) * 8;
    float acc[8][8];
#pragma unroll
    for (int i = 0; i < 8; ++i)
#pragma unroll
        for (int j = 0; j < 8; ++j) acc[i][j] = 0.f;
    for (int k0 = 0; k0 < Fc; k0 += KSTEP) {
        const float4 av = aptr ? *(const float4*)(aptr + k0 + akq) : make_float4(0.f,0.f,0.f,0.f);
        const float4 bv = *(const float4*)(bptr + (size_t)k0 * D_);
        __syncthreads();
        As[akq+0][arow] = av.x; As[akq+1][arow] = av.y;
        As[akq+2][arow] = av.z; As[akq+3][arow] = av.w;
        *(float4*)&Bs[brow][bcol] = bv;
        __syncthreads();
#pragma unroll
        for (int kk = 0; kk < KSTEP; ++kk) {
            const float4 a0 = *(const float4*)&As[kk][mb];
            const float4 a1 = *(const float4*)&As[kk][mb+4];
            const float4 b0 = *(const float4*)&Bs[kk][nb];
            const float4 b1v = *(const float4*)&Bs[kk][nb+4];
            const float af[8] = {a0.x,a0.y,a0.z,a0.w,a1.x,a1.y,a1.z,a1.w};
            const float bf[8] = {b0.x,b0.y,b0.z,b0.w,b1v.x,b1v.y,b1v.z,b1v.w};
#pragma unroll
            for (int i = 0; i < 8; ++i)
#pragma unroll
                for (int j = 0; j < 8; ++j) acc[i][j] = fmaf(af[i], bf[j], acc[i][j]);
        }
    }
#pragma unroll
    for (int i = 0; i < 8; ++i) {
        const int r = r0 + mb + i;
        if (r < cnt) {
            const size_t s = (size_t)(base + r);
            const float lw = list_w[s];
            const size_t po = s * (size_t)D_ + dcol + nb;
#pragma unroll
            for (int j = 0; j < 8; ++j) {
                float v = acc[i][j] * lw;
                if (first) v += lw * b2[(size_t)e * D_ + dcol + nb + j];
                part[po + j] = first ? v : (part[po + j] + v);
            }
        }
    }
}

// ---------------- launch ----------------
extern "C" void kernel_launch(void* const* d_in, const int* in_sizes, int n_in,
                              void* d_out, int out_size, void* d_ws, size_t ws_size,
                              hipStream_t stream)
{
    (void)in_sizes; (void)n_in; (void)out_size;
    const float* x      = (const float*)d_in[0];
    const float* gate_w = (const float*)d_in[1];
    const float* gate_b = (const float*)d_in[2];
    const float* w1     = (const float*)d_in[3];
    const float* b1     = (const float*)d_in[4];
    const float* w2     = (const float*)d_in[5];
    const float* b2     = (const float*)d_in[6];
    float* out = (float*)d_out;
    char*  ws  = (char*)d_ws;

    size_t off = 0;
    auto alloc = [&](size_t bytes) { size_t o = off; off = (off + bytes + 255) & ~255ULL; return o; };
    const size_t o_counts = alloc(64);
    const size_t o_cursor = alloc(64);
    const size_t o_offs   = alloc(64);
    const size_t o_topi   = alloc((size_t)TK_ * 4);
    const size_t o_topw   = alloc((size_t)TK_ * 4);
    const size_t o_slot   = alloc((size_t)TK_ * 4);
    const size_t o_ltok   = alloc((size_t)(TK_ + 256) * 4);
    const size_t o_lw     = alloc((size_t)TK_ * 4);
    const size_t o_part   = alloc((size_t)TK_ * D_ * 4);
    const size_t o_xh     = alloc((size_t)T_ * D_ * 2);
    const size_t o_xl     = alloc((size_t)T_ * D_ * 2);
    const size_t o_w1h    = alloc((size_t)E_ * D_ * F_ * 2);
    const size_t o_w1l    = alloc((size_t)E_ * D_ * F_ * 2);
    const size_t o_w2h    = alloc((size_t)E_ * D_ * F_ * 2);
    const size_t o_w2l    = alloc((size_t)E_ * D_ * F_ * 2);
    const size_t fixed = off;

    int*   counts     = (int*)(ws + o_counts);
    int*   cursor     = (int*)(ws + o_cursor);
    int*   offsets    = (int*)(ws + o_offs);
    int*   topi       = (int*)(ws + o_topi);
    float* topw       = (float*)(ws + o_topw);
    int*   slot_of    = (int*)(ws + o_slot);
    int*   list_token = (int*)(ws + o_ltok);
    float* list_w     = (float*)(ws + o_lw);
    float* part       = (float*)(ws + o_part);

    hipMemsetAsync(counts, 0, 64, stream);
    gate_kernel<<<T_/4, 256, 0, stream>>>(x, gate_w, gate_b, topi, topw, counts);
    offsets_kernel<<<1, 64, 0, stream>>>(counts, offsets, cursor);
    scatter_kernel<<<T_/256, 256, 0, stream>>>(topi, topw, cursor, list_token, list_w, slot_of);

    const bool mfma_ok = fixed + (size_t)TK_ * 128 * 2 * 2 + 512 <= ws_size;
    if (mfma_ok) {
        int Fc = F_;
        while (Fc > 128 && fixed + (size_t)TK_ * Fc * 2 * 2 + 512 > ws_size) Fc >>= 1;
        unsigned short* xh   = (unsigned short*)(ws + o_xh);
        unsigned short* xl   = (unsigned short*)(ws + o_xl);
        unsigned short* w1h  = (unsigned short*)(ws + o_w1h);
        unsigned short* w1l  = (unsigned short*)(ws + o_w1l);
        unsigned short* w2h  = (unsigned short*)(ws + o_w2h);
        unsigned short* w2l  = (unsigned short*)(ws + o_w2l);
        unsigned short* midh = (unsigned short*)(ws + fixed);
        unsigned short* midl = midh + (size_t)TK_ * Fc;

        convert_x_kernel<<<(T_*D_/4)/256, 256, 0, stream>>>(x, xh, xl);
        // w1 [e][D][F] -> w1t planes [e][F][D]; w2 [e][F][D] -> w2t planes [e][D][F]
        tconv_kernel<<<dim3(F_/64, D_/64, E_), 256, 0, stream>>>(w1, w1h, w1l, D_, F_);
        tconv_kernel<<<dim3(D_/64, F_/64, E_), 256, 0, stream>>>(w2, w2h, w2l, F_, D_);

        const int NC = F_ / Fc;
        for (int c = 0; c < NC; ++c) {
            gemm1_mfma<<<dim3(TK_/128, Fc/128, E_), 256, 0, stream>>>(
                xh, xl, w1h, w1l, b1, list_token, offsets, counts, midh, midl, c*Fc, Fc);
            gemm2_mfma<<<dim3(TK_/128, D_/128, E_), 256, 0, stream>>>(
                midh, midl, w2h, w2l, b2, list_w, offsets, counts, part, c*Fc, Fc, c == 0);
        }
    } else {
        // fp32 fallback if workspace is small
        float* mid = (float*)(ws + o_xh);   // reuse tail of ws for fp32 mid
        size_t avail = (ws_size > o_xh) ? ws_size - o_xh : 0;
        int Fc = 1024;
        while (Fc > 128 && (size_t)TK_ * Fc * 4 > avail) Fc >>= 1;
        const int NC = F_ / Fc;
        for (int c = 0; c < NC; ++c) {
            gemm1_f32<<<dim3(TK_/TILE, Fc/TILE, E_), 256, 0, stream>>>(
                x, w1, b1, list_token, offsets, counts, mid, c*Fc, Fc);
            gemm2_f32<<<dim3(TK_/TILE, D_/TILE, E_), 256, 0, stream>>>(
                mid, w2, b2, list_w, offsets, counts, part, c*Fc, Fc, c == 0);
        }
    }
    combine_kernel<<<(T_*D_/4)/256, 256, 0, stream>>>(part, slot_of, out);
}

// Round 9
// 2118.956 us; speedup vs baseline: 1.1506x; 1.1506x over previous
//
#include <hip/hip_runtime.h>

#define B_ 4
#define S_ 2048
#define T_ (B_*S_)      // 8192 tokens
#define D_ 1024
#define E_ 8
#define F_ 4096
#define K_ 2
#define TK_ (T_*K_)     // 16384 slots

typedef __attribute__((ext_vector_type(8))) short short8;
typedef __attribute__((ext_vector_type(4))) float f32x4;

__device__ __forceinline__ unsigned short bf16rn(float f) {
    unsigned int u = __builtin_bit_cast(unsigned int, f);
    u = u + 0x7FFFu + ((u >> 16) & 1u);
    return (unsigned short)(u >> 16);
}
__device__ __forceinline__ float bf16tof(unsigned short h) {
    unsigned int u = ((unsigned int)h) << 16;
    return __builtin_bit_cast(float, u);
}

#define GLOAD16(gp, lp) __builtin_amdgcn_global_load_lds( \
    (const __attribute__((address_space(1))) unsigned int*)(gp), \
    (__attribute__((address_space(3))) unsigned int*)(lp), 16, 0, 0)

// ---------------- gating: logits -> softmax -> top2 -> renorm ----------------
__global__ void gate_kernel(const float* __restrict__ x, const float* __restrict__ gw,
                            const float* __restrict__ gb, int* __restrict__ topi,
                            float* __restrict__ topw, int* __restrict__ counts)
{
    const int gid  = blockIdx.x * blockDim.x + threadIdx.x;
    const int t    = gid >> 6;            // one wave per token
    const int lane = threadIdx.x & 63;
    if (t >= T_) return;
    const float* xr = x + (size_t)t * D_;
    float p[E_];
#pragma unroll
    for (int e = 0; e < E_; ++e) p[e] = 0.f;
    for (int j = 0; j < D_ / 64; ++j) {
        const int d = j * 64 + lane;
        const float xv = xr[d];
        const float* g = gw + (size_t)d * E_;
#pragma unroll
        for (int e = 0; e < E_; ++e) p[e] += xv * g[e];
    }
#pragma unroll
    for (int off = 32; off > 0; off >>= 1) {
#pragma unroll
        for (int e = 0; e < E_; ++e) p[e] += __shfl_xor(p[e], off);
    }
    if (lane == 0) {
#pragma unroll
        for (int e = 0; e < E_; ++e) p[e] += gb[e];
        float m = p[0];
#pragma unroll
        for (int e = 1; e < E_; ++e) m = fmaxf(m, p[e]);
        float ex[E_];
#pragma unroll
        for (int e = 0; e < E_; ++e) ex[e] = expf(p[e] - m);
        int i0 = 0; float v0 = ex[0];
#pragma unroll
        for (int e = 1; e < E_; ++e) if (ex[e] > v0) { v0 = ex[e]; i0 = e; }
        int i1 = -1; float v1 = -1.f;
#pragma unroll
        for (int e = 0; e < E_; ++e) if (e != i0 && ex[e] > v1) { v1 = ex[e]; i1 = e; }
        const float inv = 1.f / (v0 + v1);
        topi[t*2]   = i0; topi[t*2+1] = i1;
        topw[t*2]   = v0 * inv; topw[t*2+1] = v1 * inv;
        atomicAdd(&counts[i0], 1);
        atomicAdd(&counts[i1], 1);
    }
}

__global__ void offsets_kernel(const int* __restrict__ counts, int* __restrict__ offsets,
                               int* __restrict__ cursor)
{
    if (threadIdx.x == 0 && blockIdx.x == 0) {
        int acc = 0;
        for (int e = 0; e < E_; ++e) { offsets[e] = acc; cursor[e] = acc; acc += counts[e]; }
    }
}

__global__ void scatter_kernel(const int* __restrict__ topi, const float* __restrict__ topw,
                               int* __restrict__ cursor, int* __restrict__ list_token,
                               float* __restrict__ list_w, int* __restrict__ slot_of)
{
    const int t = blockIdx.x * blockDim.x + threadIdx.x;
    if (t >= T_) return;
#pragma unroll
    for (int k = 0; k < K_; ++k) {
        const int e = topi[t*2 + k];
        const int s = atomicAdd(&cursor[e], 1);
        list_token[s] = t;
        list_w[s]     = topw[t*2 + k];
        slot_of[t*2 + k] = s;
    }
}

// ---------------- converts: fp32 -> split bf16 hi/lo ----------------
__global__ void convert_x_kernel(const float* __restrict__ x,
                                 unsigned short* __restrict__ xh,
                                 unsigned short* __restrict__ xl)
{
    const size_t i = (size_t)blockIdx.x * blockDim.x + threadIdx.x;  // one float4 each
    const float4 v = ((const float4*)x)[i];
    ushort4 h, l;
    h.x = bf16rn(v.x); l.x = bf16rn(v.x - bf16tof(h.x));
    h.y = bf16rn(v.y); l.y = bf16rn(v.y - bf16tof(h.y));
    h.z = bf16rn(v.z); l.z = bf16rn(v.z - bf16tof(h.z));
    h.w = bf16rn(v.w); l.w = bf16rn(v.w - bf16tof(h.w));
    ((ushort4*)xh)[i] = h;
    ((ushort4*)xl)[i] = l;
}

// in [e][R][C] fp32 -> oh/ol [e][C][R] bf16 (transpose+split) via LDS.
// 64x64 tile, 256 threads. Read: 16 lanes x float4 = 256B contiguous along C.
// Write: lanes vary in r -> 16 lanes x ushort4 = 128B contiguous along R.
__global__ __launch_bounds__(256) void tconv_kernel(const float* __restrict__ in,
                                                    unsigned short* __restrict__ oh,
                                                    unsigned short* __restrict__ ol,
                                                    int R, int C)
{
    const int e = blockIdx.z;
    const size_t eb = (size_t)e * R * C;
    const int c0 = blockIdx.x * 64, r0 = blockIdx.y * 64;
    __shared__ float t[64][72];            // pad 72: 16B-aligned rows, spreads banks
    const int tr  = threadIdx.x >> 4;      // 0..15
    const int tc4 = (threadIdx.x & 15) * 4;
#pragma unroll
    for (int i = 0; i < 4; ++i) {
        const float4 v = *(const float4*)&in[eb + (size_t)(r0 + tr + 16*i) * C + c0 + tc4];
        *(float4*)&t[tr + 16*i][tc4] = v;
    }
    __syncthreads();
    const int cc  = threadIdx.x >> 4;      // 0..15
    const int rq4 = (threadIdx.x & 15) * 4;
#pragma unroll
    for (int i = 0; i < 4; ++i) {
        const int c = cc + 16*i;
        ushort4 h, l;
        float f;
        f = t[rq4+0][c]; h.x = bf16rn(f); l.x = bf16rn(f - bf16tof(h.x));
        f = t[rq4+1][c]; h.y = bf16rn(f); l.y = bf16rn(f - bf16tof(h.y));
        f = t[rq4+2][c]; h.z = bf16rn(f); l.z = bf16rn(f - bf16tof(h.z));
        f = t[rq4+3][c]; h.w = bf16rn(f); l.w = bf16rn(f - bf16tof(h.w));
        const size_t o = eb + (size_t)(c0 + c) * R + r0 + rq4;
        *(ushort4*)&oh[o] = h;
        *(ushort4*)&ol[o] = l;
    }
}

// ---------------- MFMA GEMM1: mid = relu(x_gathered @ w1t^T + b1), split-3 ----------------
// Round-3 proven structure: 128x128x32 tiles, 4 waves, single-buffered 32KiB LDS.
__global__ __launch_bounds__(256, 2) void gemm1_mfma(
    const unsigned short* __restrict__ xh, const unsigned short* __restrict__ xl,
    const unsigned short* __restrict__ w1h, const unsigned short* __restrict__ w1l,
    const float* __restrict__ b1,
    const int* __restrict__ list_token, const int* __restrict__ offsets,
    const int* __restrict__ counts,
    unsigned short* __restrict__ midh, unsigned short* __restrict__ midl,
    int f0, int Fc)
{
    const int e   = blockIdx.z;
    const int cnt = counts[e];
    const int r0  = blockIdx.x * 128;
    if (r0 >= cnt) return;
    const int base = offsets[e];
    const int fcol = f0 + blockIdx.y * 128;

    __shared__ unsigned short lds[4 * 4096];   // 32 KiB

    const int tid = threadIdx.x;
    const int w = tid >> 6, l = tid & 63;

    // --- staging setup: wave w owns plane w (0:Ah 1:Al 2:Bh 3:Bl) ---
    const unsigned short* gsrc[8];
    {
        const unsigned short* Abase = (w == 0) ? xh : xl;
        const unsigned short* Bbase = (w == 2) ? w1h : w1l;
        const int jr = l >> 2, pos = l & 3;
#pragma unroll
        for (int j = 0; j < 8; ++j) {
            const int r  = j * 16 + jr;
            const int kg = pos ^ ((r >> 1) & 3);      // source pre-swizzle (involution)
            if (w < 2) {
                int idx = base + r0 + r; if (idx > TK_ - 1) idx = TK_ - 1;
                const int tok = list_token[idx];
                gsrc[j] = Abase + (size_t)tok * D_ + kg * 8;
            } else {
                gsrc[j] = Bbase + ((size_t)e * F_ + fcol + r) * D_ + kg * 8;
            }
        }
    }
    unsigned short* ldst[8];
#pragma unroll
    for (int j = 0; j < 8; ++j) ldst[j] = &lds[w * 4096 + j * 512];

    // --- fragment LDS indices (swizzled read, invariant over k0) ---
    const int wr = w >> 1, wc = w & 1;
    int idxA[4], idxB[4];
#pragma unroll
    for (int m = 0; m < 4; ++m) {
        const int row = wr * 64 + m * 16 + (l & 15);
        const int kgr = (l >> 4) ^ ((row >> 1) & 3);
        idxA[m] = row * 32 + kgr * 8;
    }
#pragma unroll
    for (int n = 0; n < 4; ++n) {
        const int row = wc * 64 + n * 16 + (l & 15);
        const int kgr = (l >> 4) ^ ((row >> 1) & 3);
        idxB[n] = row * 32 + kgr * 8;
    }

    f32x4 acc[4][4];
#pragma unroll
    for (int m = 0; m < 4; ++m)
#pragma unroll
        for (int n = 0; n < 4; ++n) { f32x4 z = {0.f,0.f,0.f,0.f}; acc[m][n] = z; }

    for (int k0 = 0; k0 < D_; k0 += 32) {
#pragma unroll
        for (int j = 0; j < 8; ++j) GLOAD16(gsrc[j] + k0, ldst[j]);
        __syncthreads();                      // drains vmcnt: tile ready
        short8 ah[4], al[4], bh[4], bl[4];
#pragma unroll
        for (int m = 0; m < 4; ++m) {
            ah[m] = *(const short8*)&lds[0 * 4096 + idxA[m]];
            al[m] = *(const short8*)&lds[1 * 4096 + idxA[m]];
        }
#pragma unroll
        for (int n = 0; n < 4; ++n) {
            bh[n] = *(const short8*)&lds[2 * 4096 + idxB[n]];
            bl[n] = *(const short8*)&lds[3 * 4096 + idxB[n]];
        }
#pragma unroll
        for (int m = 0; m < 4; ++m)
#pragma unroll
            for (int n = 0; n < 4; ++n) {
                acc[m][n] = __builtin_amdgcn_mfma_f32_16x16x32_bf16(ah[m], bh[n], acc[m][n], 0, 0, 0);
                acc[m][n] = __builtin_amdgcn_mfma_f32_16x16x32_bf16(ah[m], bl[n], acc[m][n], 0, 0, 0);
                acc[m][n] = __builtin_amdgcn_mfma_f32_16x16x32_bf16(al[m], bh[n], acc[m][n], 0, 0, 0);
            }
        __syncthreads();                      // compute done; safe to overwrite
    }

    // --- epilogue: +bias, relu, split to bf16 hi/lo, store mid ---
    const float* b1e = b1 + (size_t)e * F_;
#pragma unroll
    for (int n = 0; n < 4; ++n) {
        const int fg = fcol + wc * 64 + n * 16 + (l & 15);
        const float bias = b1e[fg];
        const int fl = fg - f0;
#pragma unroll
        for (int m = 0; m < 4; ++m)
#pragma unroll
            for (int q = 0; q < 4; ++q) {
                const int rr = r0 + wr * 64 + m * 16 + (l >> 4) * 4 + q;
                if (rr < cnt) {
                    float v = acc[m][n][q] + bias;
                    v = fmaxf(v, 0.f);
                    const unsigned short h = bf16rn(v);
                    const unsigned short lo = bf16rn(v - bf16tof(h));
                    const size_t o = (size_t)(base + rr) * Fc + fl;
                    midh[o] = h; midl[o] = lo;
                }
            }
    }
}

// ---------------- MFMA GEMM2: part[slot] (+)= lw*(mid @ w2t^T + b2), split-3 ----------------
// Grid TRANSPOSED vs gemm1: x = dcol panels (8), y = row panels. Consecutive blocks
// share the same 4MB mid row-panel (L3-absorbed) instead of re-fetching mid 8x.
__global__ __launch_bounds__(256, 2) void gemm2_mfma(
    const unsigned short* __restrict__ midh, const unsigned short* __restrict__ midl,
    const unsigned short* __restrict__ w2h, const unsigned short* __restrict__ w2l,
    const float* __restrict__ b2, const float* __restrict__ list_w,
    const int* __restrict__ offsets, const int* __restrict__ counts,
    float* __restrict__ part, int f0, int Fc, int first)
{
    const int e   = blockIdx.z;
    const int cnt = counts[e];
    const int r0  = blockIdx.y * 128;          // transposed
    if (r0 >= cnt) return;
    const int base = offsets[e];
    const int dcol = blockIdx.x * 128;         // transposed

    __shared__ unsigned short lds[4 * 4096];

    const int tid = threadIdx.x;
    const int w = tid >> 6, l = tid & 63;

    const unsigned short* gsrc[8];
    {
        const unsigned short* Abase = (w == 0) ? midh : midl;
        const unsigned short* Bbase = (w == 2) ? w2h : w2l;
        const int jr = l >> 2, pos = l & 3;
#pragma unroll
        for (int j = 0; j < 8; ++j) {
            const int r  = j * 16 + jr;
            const int kg = pos ^ ((r >> 1) & 3);
            if (w < 2) {
                int slot = base + r0 + r; if (slot > TK_ - 1) slot = TK_ - 1;
                gsrc[j] = Abase + (size_t)slot * Fc + kg * 8;
            } else {
                gsrc[j] = Bbase + ((size_t)e * D_ + dcol + r) * F_ + f0 + kg * 8;
            }
        }
    }
    unsigned short* ldst[8];
#pragma unroll
    for (int j = 0; j < 8; ++j) ldst[j] = &lds[w * 4096 + j * 512];

    const int wr = w >> 1, wc = w & 1;
    int idxA[4], idxB[4];
#pragma unroll
    for (int m = 0; m < 4; ++m) {
        const int row = wr * 64 + m * 16 + (l & 15);
        const int kgr = (l >> 4) ^ ((row >> 1) & 3);
        idxA[m] = row * 32 + kgr * 8;
    }
#pragma unroll
    for (int n = 0; n < 4; ++n) {
        const int row = wc * 64 + n * 16 + (l & 15);
        const int kgr = (l >> 4) ^ ((row >> 1) & 3);
        idxB[n] = row * 32 + kgr * 8;
    }

    f32x4 acc[4][4];
#pragma unroll
    for (int m = 0; m < 4; ++m)
#pragma unroll
        for (int n = 0; n < 4; ++n) { f32x4 z = {0.f,0.f,0.f,0.f}; acc[m][n] = z; }

    for (int k0 = 0; k0 < Fc; k0 += 32) {
#pragma unroll
        for (int j = 0; j < 8; ++j) GLOAD16(gsrc[j] + k0, ldst[j]);
        __syncthreads();
        short8 ah[4], al[4], bh[4], bl[4];
#pragma unroll
        for (int m = 0; m < 4; ++m) {
            ah[m] = *(const short8*)&lds[0 * 4096 + idxA[m]];
            al[m] = *(const short8*)&lds[1 * 4096 + idxA[m]];
        }
#pragma unroll
        for (int n = 0; n < 4; ++n) {
            bh[n] = *(const short8*)&lds[2 * 4096 + idxB[n]];
            bl[n] = *(const short8*)&lds[3 * 4096 + idxB[n]];
        }
#pragma unroll
        for (int m = 0; m < 4; ++m)
#pragma unroll
            for (int n = 0; n < 4; ++n) {
                acc[m][n] = __builtin_amdgcn_mfma_f32_16x16x32_bf16(ah[m], bh[n], acc[m][n], 0, 0, 0);
                acc[m][n] = __builtin_amdgcn_mfma_f32_16x16x32_bf16(ah[m], bl[n], acc[m][n], 0, 0, 0);
                acc[m][n] = __builtin_amdgcn_mfma_f32_16x16x32_bf16(al[m], bh[n], acc[m][n], 0, 0, 0);
            }
        __syncthreads();
    }

    float bias[4]; int dg[4];
#pragma unroll
    for (int n = 0; n < 4; ++n) {
        dg[n] = dcol + wc * 64 + n * 16 + (l & 15);
        bias[n] = b2[(size_t)e * D_ + dg[n]];
    }
#pragma unroll
    for (int m = 0; m < 4; ++m)
#pragma unroll
        for (int q = 0; q < 4; ++q) {
            const int rr = r0 + wr * 64 + m * 16 + (l >> 4) * 4 + q;
            if (rr < cnt) {
                const size_t s = (size_t)(base + rr);
                const float lw = list_w[s];
#pragma unroll
                for (int n = 0; n < 4; ++n) {
                    float v = acc[m][n][q] * lw;
                    if (first) v += lw * bias[n];
                    const size_t o = s * D_ + dg[n];
                    part[o] = first ? v : (part[o] + v);
                }
            }
        }
}

// ---------------- combine ----------------
__global__ void combine_kernel(const float* __restrict__ part, const int* __restrict__ slot_of,
                               float* __restrict__ out)
{
    const int idx = blockIdx.x * blockDim.x + threadIdx.x;
    const int t  = idx >> 8;            // D/4 = 256 float4 per token
    const int dq = idx & 255;
    const float4* p4 = (const float4*)part;
    const float4 a = p4[(size_t)slot_of[t*2]   * 256 + dq];
    const float4 b = p4[(size_t)slot_of[t*2+1] * 256 + dq];
    float4 r; r.x = a.x + b.x; r.y = a.y + b.y; r.z = a.z + b.z; r.w = a.w + b.w;
    ((float4*)out)[(size_t)t * 256 + dq] = r;
}

// ---------------- fallback fp32 GEMMs (used only if ws too small) ----------------
#define TILE 128
#define KSTEP 8
__global__ __launch_bounds__(256) void gemm1_f32(
    const float* __restrict__ x, const float* __restrict__ w1, const float* __restrict__ b1,
    const int* __restrict__ list_token, const int* __restrict__ offsets,
    const int* __restrict__ counts, float* __restrict__ mid, int f0, int Fc)
{
    const int e   = blockIdx.z;
    const int cnt = counts[e];
    const int r0  = blockIdx.x * TILE;
    if (r0 >= cnt) return;
    const int base = offsets[e];
    const int fcol = f0 + blockIdx.y * TILE;
    const int tid  = threadIdx.x;
    __shared__ float As[KSTEP][TILE + 4];
    __shared__ float Bs[KSTEP][TILE + 4];
    const int arow = tid >> 1;
    const int akq  = (tid & 1) * 4;
    const float* aptr = nullptr;
    if (r0 + arow < cnt) aptr = x + (size_t)list_token[base + r0 + arow] * D_;
    const int brow = tid >> 5;
    const int bcol = (tid & 31) * 4;
    const float* bptr = w1 + ((size_t)e * D_ + brow) * F_ + fcol + bcol;
    const int mb = (tid >> 4) * 8, nb = (tid & 15) * 8;
    float acc[8][8];
#pragma unroll
    for (int i = 0; i < 8; ++i)
#pragma unroll
        for (int j = 0; j < 8; ++j) acc[i][j] = 0.f;
    for (int k0 = 0; k0 < D_; k0 += KSTEP) {
        const float4 av = aptr ? *(const float4*)(aptr + k0 + akq) : make_float4(0.f,0.f,0.f,0.f);
        const float4 bv = *(const float4*)(bptr + (size_t)k0 * F_);
        __syncthreads();
        As[akq+0][arow] = av.x; As[akq+1][arow] = av.y;
        As[akq+2][arow] = av.z; As[akq+3][arow] = av.w;
        *(float4*)&Bs[brow][bcol] = bv;
        __syncthreads();
#pragma unroll
        for (int kk = 0; kk < KSTEP; ++kk) {
            const float4 a0 = *(const float4*)&As[kk][mb];
            const float4 a1 = *(const float4*)&As[kk][mb+4];
            const float4 b0 = *(const float4*)&Bs[kk][nb];
            const float4 b1v = *(const float4*)&Bs[kk][nb+4];
            const float af[8] = {a0.x,a0.y,a0.z,a0.w,a1.x,a1.y,a1.z,a1.w};
            const float bf[8] = {b0.x,b0.y,b0.z,b0.w,b1v.x,b1v.y,b1v.z,b1v.w};
#pragma unroll
            for (int i = 0; i < 8; ++i)
#pragma unroll
                for (int j = 0; j < 8; ++j) acc[i][j] = fmaf(af[i], bf[j], acc[i][j]);
        }
    }
    const int fc_local = fcol - f0;
#pragma unroll
    for (int i = 0; i < 8; ++i) {
        const int r = r0 + mb + i;
        if (r < cnt) {
            const size_t s = (size_t)(base + r);
            const size_t off = s * (size_t)Fc + fc_local + nb;
#pragma unroll
            for (int j = 0; j < 8; ++j) {
                const float v = acc[i][j] + b1[(size_t)e * F_ + fcol + nb + j];
                mid[off + j] = fmaxf(v, 0.f);
            }
        }
    }
}

__global__ __launch_bounds__(256) void gemm2_f32(
    const float* __restrict__ mid, const float* __restrict__ w2, const float* __restrict__ b2,
    const float* __restrict__ list_w, const int* __restrict__ offsets,
    const int* __restrict__ counts, float* __restrict__ part, int f0, int Fc, int first)
{
    const int e   = blockIdx.z;
    const int cnt = counts[e];
    const int r0  = blockIdx.x * TILE;
    if (r0 >= cnt) return;
    const int base = offsets[e];
    const int dcol = blockIdx.y * TILE;
    const int tid  = threadIdx.x;
    __shared__ float As[KSTEP][TILE + 4];
    __shared__ float Bs[KSTEP][TILE + 4];
    const int arow = tid >> 1;
    const int akq  = (tid & 1) * 4;
    const float* aptr = nullptr;
    if (r0 + arow < cnt) aptr = mid + (size_t)(base + r0 + arow) * Fc;
    const int brow = tid >> 5;
    const int bcol = (tid & 31) * 4;
    const float* bptr = w2 + ((size_t)e * F_ + f0 + brow) * D_ + dcol + bcol;
    const int mb = (tid >> 4) * 8, nb = (tid & 15) * 8;
    float acc[8][8];
#pragma unroll
    for (int i = 0; i < 8; ++i)
#pragma unroll
        for (int j = 0; j < 8; ++j) acc[i][j] = 0.f;
    for (int k0 = 0; k0 < Fc; k0 += KSTEP) {
        const float4 av = aptr ? *(const float4*)(aptr + k0 + akq) : make_float4(0.f,0.f,0.f,0.f);
        const float4 bv = *(const float4*)(bptr + (size_t)k0 * D_);
        __syncthreads();
        As[akq+0][arow] = av.x; As[akq+1][arow] = av.y;
        As[akq+2][arow] = av.z; As[akq+3][arow] = av.w;
        *(float4*)&Bs[brow][bcol] = bv;
        __syncthreads();
#pragma unroll
        for (int kk = 0; kk < KSTEP; ++kk) {
            const float4 a0 = *(const float4*)&As[kk][mb];
            const float4 a1 = *(const float4*)&As[kk][mb+4];
            const float4 b0 = *(const float4*)&Bs[kk][nb];
            const float4 b1v = *(const float4*)&Bs[kk][nb+4];
            const float af[8] = {a0.x,a0.y,a0.z,a0.w,a1.x,a1.y,a1.z,a1.w};
            const float bf[8] = {b0.x,b0.y,b0.z,b0.w,b1v.x,b1v.y,b1v.z,b1v.w};
#pragma unroll
            for (int i = 0; i < 8; ++i)
#pragma unroll
                for (int j = 0; j < 8; ++j) acc[i][j] = fmaf(af[i], bf[j], acc[i][j]);
        }
    }
#pragma unroll
    for (int i = 0; i < 8; ++i) {
        const int r = r0 + mb + i;
        if (r < cnt) {
            const size_t s = (size_t)(base + r);
            const float lw = list_w[s];
            const size_t po = s * (size_t)D_ + dcol + nb;
#pragma unroll
            for (int j = 0; j < 8; ++j) {
                float v = acc[i][j] * lw;
                if (first) v += lw * b2[(size_t)e * D_ + dcol + nb + j];
                part[po + j] = first ? v : (part[po + j] + v);
            }
        }
    }
}

// ---------------- launch ----------------
extern "C" void kernel_launch(void* const* d_in, const int* in_sizes, int n_in,
                              void* d_out, int out_size, void* d_ws, size_t ws_size,
                              hipStream_t stream)
{
    (void)in_sizes; (void)n_in; (void)out_size;
    const float* x      = (const float*)d_in[0];
    const float* gate_w = (const float*)d_in[1];
    const float* gate_b = (const float*)d_in[2];
    const float* w1     = (const float*)d_in[3];
    const float* b1     = (const float*)d_in[4];
    const float* w2     = (const float*)d_in[5];
    const float* b2     = (const float*)d_in[6];
    float* out = (float*)d_out;
    char*  ws  = (char*)d_ws;

    size_t off = 0;
    auto alloc = [&](size_t bytes) { size_t o = off; off = (off + bytes + 255) & ~255ULL; return o; };
    const size_t o_counts = alloc(64);
    const size_t o_cursor = alloc(64);
    const size_t o_offs   = alloc(64);
    const size_t o_topi   = alloc((size_t)TK_ * 4);
    const size_t o_topw   = alloc((size_t)TK_ * 4);
    const size_t o_slot   = alloc((size_t)TK_ * 4);
    const size_t o_ltok   = alloc((size_t)(TK_ + 256) * 4);
    const size_t o_lw     = alloc((size_t)TK_ * 4);
    const size_t o_part   = alloc((size_t)TK_ * D_ * 4);
    const size_t o_xh     = alloc((size_t)T_ * D_ * 2);
    const size_t o_xl     = alloc((size_t)T_ * D_ * 2);
    const size_t o_w1h    = alloc((size_t)E_ * D_ * F_ * 2);
    const size_t o_w1l    = alloc((size_t)E_ * D_ * F_ * 2);
    const size_t o_w2h    = alloc((size_t)E_ * D_ * F_ * 2);
    const size_t o_w2l    = alloc((size_t)E_ * D_ * F_ * 2);
    const size_t fixed = off;

    int*   counts     = (int*)(ws + o_counts);
    int*   cursor     = (int*)(ws + o_cursor);
    int*   offsets    = (int*)(ws + o_offs);
    int*   topi       = (int*)(ws + o_topi);
    float* topw       = (float*)(ws + o_topw);
    int*   slot_of    = (int*)(ws + o_slot);
    int*   list_token = (int*)(ws + o_ltok);
    float* list_w     = (float*)(ws + o_lw);
    float* part       = (float*)(ws + o_part);

    hipMemsetAsync(counts, 0, 64, stream);
    gate_kernel<<<T_/4, 256, 0, stream>>>(x, gate_w, gate_b, topi, topw, counts);
    offsets_kernel<<<1, 64, 0, stream>>>(counts, offsets, cursor);
    scatter_kernel<<<T_/256, 256, 0, stream>>>(topi, topw, cursor, list_token, list_w, slot_of);

    const bool mfma_ok = fixed + (size_t)TK_ * 128 * 2 * 2 + 512 <= ws_size;
    if (mfma_ok) {
        int Fc = F_;
        while (Fc > 128 && fixed + (size_t)TK_ * Fc * 2 * 2 + 512 > ws_size) Fc >>= 1;
        unsigned short* xh   = (unsigned short*)(ws + o_xh);
        unsigned short* xl   = (unsigned short*)(ws + o_xl);
        unsigned short* w1h  = (unsigned short*)(ws + o_w1h);
        unsigned short* w1l  = (unsigned short*)(ws + o_w1l);
        unsigned short* w2h  = (unsigned short*)(ws + o_w2h);
        unsigned short* w2l  = (unsigned short*)(ws + o_w2l);
        unsigned short* midh = (unsigned short*)(ws + fixed);
        unsigned short* midl = midh + (size_t)TK_ * Fc;

        convert_x_kernel<<<(T_*D_/4)/256, 256, 0, stream>>>(x, xh, xl);
        // w1 [e][D][F] -> w1t planes [e][F][D]; w2 [e][F][D] -> w2t planes [e][D][F]
        tconv_kernel<<<dim3(F_/64, D_/64, E_), 256, 0, stream>>>(w1, w1h, w1l, D_, F_);
        tconv_kernel<<<dim3(D_/64, F_/64, E_), 256, 0, stream>>>(w2, w2h, w2l, F_, D_);

        const int NC = F_ / Fc;
        for (int c = 0; c < NC; ++c) {
            gemm1_mfma<<<dim3(TK_/128, Fc/128, E_), 256, 0, stream>>>(
                xh, xl, w1h, w1l, b1, list_token, offsets, counts, midh, midl, c*Fc, Fc);
            // transposed grid: x = D panels, y = row panels
            gemm2_mfma<<<dim3(D_/128, TK_/128, E_), 256, 0, stream>>>(
                midh, midl, w2h, w2l, b2, list_w, offsets, counts, part, c*Fc, Fc, c == 0);
        }
    } else {
        // fp32 fallback if workspace is small
        float* mid = (float*)(ws + o_xh);   // reuse tail of ws for fp32 mid
        size_t avail = (ws_size > o_xh) ? ws_size - o_xh : 0;
        int Fc = 1024;
        while (Fc > 128 && (size_t)TK_ * Fc * 4 > avail) Fc >>= 1;
        const int NC = F_ / Fc;
        for (int c = 0; c < NC; ++c) {
            gemm1_f32<<<dim3(TK_/TILE, Fc/TILE, E_), 256, 0, stream>>>(
                x, w1, b1, list_token, offsets, counts, mid, c*Fc, Fc);
            gemm2_f32<<<dim3(TK_/TILE, D_/TILE, E_), 256, 0, stream>>>(
                mid, w2, b2, list_w, offsets, counts, part, c*Fc, Fc, c == 0);
        }
    }
    combine_kernel<<<(T_*D_/4)/256, 256, 0, stream>>>(part, slot_of, out);
}